// Round 5
// baseline (823.457 us; speedup 1.0000x reference)
//
#include <hip/hip_runtime.h>

// GNN layer: out = segment_sum(nf[src], dst) @ W.T + b
// N=50000, E=800000, D=128.
// R5: kill the CSR sort (R4: hist+scan+scatter ~100us, scatter WRITE 52MB).
// Edges pack to uint32 (src,dst both <2^16). k_bucket partitions into 196
// buckets of 256 nodes with exclusive per-(block,bucket) segments (dense
// writes). k_agg: one block/bucket, fp32 LDS accumulator (128KB), ds_add_f32,
// bf16 output. Edge buffer lives in d_out (dead until k_linear overwrites).

constexpr int NN = 50000;
constexpr int NE = 800000;
constexpr int D  = 128;

constexpr int BS  = 256;                       // nodes per bucket
constexpr int NB  = (NN + BS - 1) / BS;        // 196 buckets
constexpr int CAP = 8192;                      // cap/bucket (mean 4096, sd 64 -> 64 sigma)
constexpr int EPB = 4096;                      // edges per pass-A block
constexpr int NBLK_A = (NE + EPB - 1) / EPB;   // 196

typedef __attribute__((ext_vector_type(8))) short bf16x8;
typedef __attribute__((ext_vector_type(4))) float f32x4;

__device__ inline unsigned short f2bf(float f) {           // RNE
    unsigned u = __float_as_uint(f);
    return (unsigned short)((u + 0x7fffu + ((u >> 16) & 1u)) >> 16);
}
__device__ inline float bflo(unsigned v) { return __uint_as_float(v << 16); }
__device__ inline float bfhi(unsigned v) { return __uint_as_float(v & 0xffff0000u); }

// ---- 0. prep: nf->bf16, W->bf16, cursor[b] = b*CAP ------------------------
constexpr int NF4 = NN * D / 4;        // 1,600,000
constexpr int W4  = D * D / 4;         // 4,096
constexpr int PREP_TOT = NF4 + W4 + NB;

__global__ __launch_bounds__(256) void k_prep(const float* __restrict__ nf,
                                              const float* __restrict__ W,
                                              ushort* __restrict__ nfh,
                                              ushort* __restrict__ Wh,
                                              int* __restrict__ cursor) {
    int t = blockIdx.x * 256 + threadIdx.x;
    if (t < NF4) {
        float4 v = ((const float4*)nf)[t];
        ((ushort4*)nfh)[t] = make_ushort4(f2bf(v.x), f2bf(v.y), f2bf(v.z), f2bf(v.w));
    } else if (t < NF4 + W4) {
        int i = t - NF4;
        float4 v = ((const float4*)W)[i];
        ((ushort4*)Wh)[i] = make_ushort4(f2bf(v.x), f2bf(v.y), f2bf(v.z), f2bf(v.w));
    } else if (t < PREP_TOT) {
        int b = t - NF4 - W4;
        cursor[b] = b * CAP;
    }
}

// ---- 1. bucket partition: pk=(dst<<16)|src into exclusive segments --------
__global__ __launch_bounds__(256) void k_bucket(const int* __restrict__ ei,
                                                int* __restrict__ cursor,
                                                unsigned* __restrict__ buf) {
    __shared__ int h[NB];       // per-block bucket histogram
    __shared__ int gbase[NB];   // reserved global base per bucket
    __shared__ int lcur[NB];    // local write cursor per bucket
    int t = threadIdx.x;
    for (int i = t; i < NB; i += 256) { h[i] = 0; lcur[i] = 0; }
    __syncthreads();

    const int e0 = blockIdx.x * EPB;
    unsigned pk[16];
    #pragma unroll
    for (int j = 0; j < 16; ++j) {
        int e = e0 + j * 256 + t;
        if (e < NE) {
            unsigned s = (unsigned)ei[e];
            unsigned d = (unsigned)ei[NE + e];
            pk[j] = (d << 16) | s;                 // bucket = pk >> 24
            atomicAdd(&h[pk[j] >> 24], 1);
        }
    }
    __syncthreads();
    for (int i = t; i < NB; i += 256)
        if (h[i] > 0) gbase[i] = atomicAdd(&cursor[i], h[i]);
    __syncthreads();
    #pragma unroll
    for (int j = 0; j < 16; ++j) {
        int e = e0 + j * 256 + t;
        if (e < NE) {
            unsigned b = pk[j] >> 24;
            int l = atomicAdd(&lcur[b], 1);
            buf[gbase[b] + l] = pk[j];             // dense, exclusive segment
        }
    }
}

// ---- 2. aggregate: one block/bucket, fp32 LDS tile, ds_add_f32 ------------
__global__ __launch_bounds__(1024) void k_agg(const unsigned* __restrict__ nfh,
                                              const int* __restrict__ cursor,
                                              const unsigned* __restrict__ buf,
                                              unsigned* __restrict__ aggh) {
    __shared__ float acc[BS * D];                  // 131072 B
    const int b    = blockIdx.x;
    const int t    = threadIdx.x;
    const int lane = t & 63;
    const int w    = t >> 6;                       // 16 waves

    for (int i = t; i < BS * D / 4; i += 1024)
        ((float4*)acc)[i] = make_float4(0.f, 0.f, 0.f, 0.f);
    __syncthreads();

    const int cnt = cursor[b] - b * CAP;
    const unsigned* mybuf = buf + b * CAP;

    for (int base = w * 64; base < cnt; base += 16 * 64) {
        unsigned pkv = 0;
        if (base + lane < cnt) pkv = mybuf[base + lane];
        int m = cnt - base; if (m > 64) m = 64;
        int j = 0;
        for (; j + 3 < m; j += 4) {                // 4 gathers in flight
            unsigned u0 = __shfl(pkv, j + 0);
            unsigned u1 = __shfl(pkv, j + 1);
            unsigned u2 = __shfl(pkv, j + 2);
            unsigned u3 = __shfl(pkv, j + 3);
            unsigned v0 = nfh[(size_t)(u0 & 0xffffu) * 64 + lane];
            unsigned v1 = nfh[(size_t)(u1 & 0xffffu) * 64 + lane];
            unsigned v2 = nfh[(size_t)(u2 & 0xffffu) * 64 + lane];
            unsigned v3 = nfh[(size_t)(u3 & 0xffffu) * 64 + lane];
            int r0 = (int)((u0 >> 16) & 255u) * D + 2 * lane;
            int r1 = (int)((u1 >> 16) & 255u) * D + 2 * lane;
            int r2 = (int)((u2 >> 16) & 255u) * D + 2 * lane;
            int r3 = (int)((u3 >> 16) & 255u) * D + 2 * lane;
            atomicAdd(&acc[r0], bflo(v0)); atomicAdd(&acc[r0 + 1], bfhi(v0));
            atomicAdd(&acc[r1], bflo(v1)); atomicAdd(&acc[r1 + 1], bfhi(v1));
            atomicAdd(&acc[r2], bflo(v2)); atomicAdd(&acc[r2 + 1], bfhi(v2));
            atomicAdd(&acc[r3], bflo(v3)); atomicAdd(&acc[r3 + 1], bfhi(v3));
        }
        for (; j < m; ++j) {
            unsigned u0 = __shfl(pkv, j);
            unsigned v0 = nfh[(size_t)(u0 & 0xffffu) * 64 + lane];
            int r0 = (int)((u0 >> 16) & 255u) * D + 2 * lane;
            atomicAdd(&acc[r0], bflo(v0)); atomicAdd(&acc[r0 + 1], bfhi(v0));
        }
    }
    __syncthreads();

    const int nodebase = b * BS;
    for (int i = t; i < BS * 64; i += 1024) {      // bf16 pack, coalesced
        int n = i >> 6, dp = i & 63;
        if (nodebase + n < NN) {
            float x = acc[n * D + 2 * dp];
            float y = acc[n * D + 2 * dp + 1];
            aggh[(size_t)(nodebase + n) * 64 + dp] =
                (unsigned)f2bf(x) | ((unsigned)f2bf(y) << 16);
        }
    }
}

// ---- 3. linear: out = aggh @ Wh.T + b  (bf16 MFMA, no LDS; R4-verified) ---
__global__ __launch_bounds__(256) void k_linear(const ushort* __restrict__ aggh,
                                                const ushort* __restrict__ Wh,
                                                const float* __restrict__ b,
                                                float* __restrict__ out) {
    int wave = threadIdx.x >> 6;
    int lane = threadIdx.x & 63;
    int R = blockIdx.x * 64 + wave * 16;
    if (R >= NN) return;
    int m = lane & 15;
    int q = lane >> 4;

    bf16x8 a[4];
    const ushort* arow = aggh + (size_t)(R + m) * D + q * 8;
    #pragma unroll
    for (int kk = 0; kk < 4; ++kk)
        a[kk] = *(const bf16x8*)(arow + kk * 32);

    #pragma unroll
    for (int c0 = 0; c0 < D; c0 += 16) {
        float bias = b[c0 + m];
        f32x4 acc = { bias, bias, bias, bias };
        const ushort* wrow = Wh + (size_t)(c0 + m) * D + q * 8;
        #pragma unroll
        for (int kk = 0; kk < 4; ++kk) {
            bf16x8 bb = *(const bf16x8*)(wrow + kk * 32);
            acc = __builtin_amdgcn_mfma_f32_16x16x32_bf16(a[kk], bb, acc, 0, 0, 0);
        }
        int row = R + q * 4;
        float* op = out + (size_t)row * D + c0 + m;
        op[0]     = acc[0];
        op[D]     = acc[1];
        op[2 * D] = acc[2];
        op[3 * D] = acc[3];
    }
}

extern "C" void kernel_launch(void* const* d_in, const int* in_sizes, int n_in,
                              void* d_out, int out_size, void* d_ws, size_t ws_size,
                              hipStream_t stream) {
    const float* nf = (const float*)d_in[0];
    const int*   ei = (const int*)d_in[1];
    const float* W  = (const float*)d_in[2];
    const float* b  = (const float*)d_in[3];
    float* out = (float*)d_out;

    // workspace: 12.8 + 0.03 + 12.8 MB + 784 B  (< 29.4 MB proven in R4)
    ushort* nfh  = (ushort*)d_ws;                 // NN*D bf16
    ushort* Wh   = nfh + (size_t)NN * D;          // D*D bf16
    ushort* aggh = Wh + D * D;                    // NN*D bf16
    int* cursor  = (int*)(aggh + (size_t)NN * D); // NB ints

    // edge buffer (196*8192*4 = 6.4 MB) lives in d_out: dead until k_linear,
    // which fully overwrites all NN*D outputs.
    unsigned* buf = (unsigned*)d_out;

    k_prep  <<<(PREP_TOT + 255) / 256, 256, 0, stream>>>(nf, W, nfh, Wh, cursor);
    k_bucket<<<NBLK_A, 256, 0, stream>>>(ei, cursor, buf);
    k_agg   <<<NB, 1024, 0, stream>>>((const unsigned*)nfh, cursor, buf, (unsigned*)aggh);
    k_linear<<<(NN + 63) / 64, 256, 0, stream>>>(aggh, Wh, b, out);
}

// Round 6
// 163.794 us; speedup vs baseline: 5.0274x; 5.0274x over previous
//
#include <hip/hip_runtime.h>

// GNN layer: out = segment_sum(nf[src], dst) @ W.T + b
// N=50000, E=800000, D=128.
// R6: revert R5's block-per-bucket aggregate (712us: 3136 waves, latency-
// starved). Keep R4's wave-per-node aggregate (50k waves). CSR build via
// R5's k_bucket (dense segment writes) + new k_sortlocal (node-sort within
// 16KB LDS-resident segment -> no write amplification; R4 scatter_idx wrote
// 52MB for a 3.2MB payload). 5 dispatches.

constexpr int NN = 50000;
constexpr int NE = 800000;
constexpr int D  = 128;

constexpr int BS  = 256;                       // nodes per bucket
constexpr int NB  = (NN + BS - 1) / BS;        // 196 buckets
constexpr int CAP = 8192;                      // edges cap/bucket (mean 4096, sd 64)
constexpr int EPB = 4096;                      // edges per k_bucket block
constexpr int NBLK_A = (NE + EPB - 1) / EPB;   // 196

typedef __attribute__((ext_vector_type(8))) short bf16x8;
typedef __attribute__((ext_vector_type(4))) float f32x4;

__device__ inline unsigned short f2bf(float f) {           // RNE
    unsigned u = __float_as_uint(f);
    return (unsigned short)((u + 0x7fffu + ((u >> 16) & 1u)) >> 16);
}
__device__ inline float bflo(unsigned v) { return __uint_as_float(v << 16); }
__device__ inline float bfhi(unsigned v) { return __uint_as_float(v & 0xffff0000u); }

// ---- 0. prep: nf->bf16, W->bf16, cursor[b]=b*CAP --------------------------
constexpr int NF4 = NN * D / 4;
constexpr int W4  = D * D / 4;
constexpr int PREP_TOT = NF4 + W4 + NB;

__global__ __launch_bounds__(256) void k_prep(const float* __restrict__ nf,
                                              const float* __restrict__ W,
                                              ushort* __restrict__ nfh,
                                              ushort* __restrict__ Wh,
                                              int* __restrict__ cursor) {
    int t = blockIdx.x * 256 + threadIdx.x;
    if (t < NF4) {
        float4 v = ((const float4*)nf)[t];
        ((ushort4*)nfh)[t] = make_ushort4(f2bf(v.x), f2bf(v.y), f2bf(v.z), f2bf(v.w));
    } else if (t < NF4 + W4) {
        int i = t - NF4;
        float4 v = ((const float4*)W)[i];
        ((ushort4*)Wh)[i] = make_ushort4(f2bf(v.x), f2bf(v.y), f2bf(v.z), f2bf(v.w));
    } else if (t < PREP_TOT) {
        int b = t - NF4 - W4;
        cursor[b] = b * CAP;
    }
}

// ---- 1. bucket partition: pk=(dst<<16)|src into exclusive dense segments --
__global__ __launch_bounds__(256) void k_bucket(const int* __restrict__ ei,
                                                int* __restrict__ cursor,
                                                unsigned* __restrict__ buf) {
    __shared__ int h[NB];
    __shared__ int gbase[NB];
    __shared__ int lcur[NB];
    int t = threadIdx.x;
    for (int i = t; i < NB; i += 256) { h[i] = 0; lcur[i] = 0; }
    __syncthreads();

    const int e0 = blockIdx.x * EPB;
    unsigned pk[16];
    #pragma unroll
    for (int j = 0; j < 16; ++j) {
        int e = e0 + j * 256 + t;
        if (e < NE) {
            unsigned s = (unsigned)ei[e];
            unsigned d = (unsigned)ei[NE + e];
            pk[j] = (d << 16) | s;                 // bucket = pk >> 24
            atomicAdd(&h[pk[j] >> 24], 1);
        }
    }
    __syncthreads();
    for (int i = t; i < NB; i += 256)
        if (h[i] > 0) gbase[i] = atomicAdd(&cursor[i], h[i]);
    __syncthreads();
    #pragma unroll
    for (int j = 0; j < 16; ++j) {
        int e = e0 + j * 256 + t;
        if (e < NE) {
            unsigned b = pk[j] >> 24;
            int l = atomicAdd(&lcur[b], 1);
            buf[gbase[b] + l] = pk[j];
        }
    }
}

// ---- 2. node-sort within each bucket segment (LDS hist+scan), emit CSR ----
__global__ __launch_bounds__(256) void k_sortlocal(const int* __restrict__ cursor,
                                                   const unsigned* __restrict__ buf,
                                                   ushort* __restrict__ srt,
                                                   int* __restrict__ beg,
                                                   int* __restrict__ end) {
    __shared__ int s[BS];       // scan workspace
    __shared__ int cur[BS];     // scatter cursors
    const int b = blockIdx.x;
    const int t = threadIdx.x;
    const int seg = b * CAP;
    const int cnt = cursor[b] - seg;

    // histogram over 256 local nodes
    s[t] = 0; __syncthreads();
    for (int e = t; e < cnt; e += 256)
        atomicAdd(&s[(buf[seg + e] >> 16) & 255u], 1);
    __syncthreads();
    int myc = s[t];
    // inclusive scan (Hillis-Steele)
    for (int off = 1; off < 256; off <<= 1) {
        int v = (t >= off) ? s[t - off] : 0;
        __syncthreads();
        s[t] += v;
        __syncthreads();
    }
    int excl = s[t] - myc;
    cur[t] = excl;
    int node = b * BS + t;
    if (node < NN) { beg[node] = seg + excl; end[node] = seg + excl + myc; }
    __syncthreads();

    // scatter into node-sorted order within the 16KB segment
    for (int e = t; e < cnt; e += 256) {
        unsigned pk = buf[seg + e];
        int n = (pk >> 16) & 255u;
        int p = atomicAdd(&cur[n], 1);
        srt[seg + p] = (ushort)(pk & 0xffffu);
    }
}

// ---- 3. aggregate: one wave/node, bf16 dword/lane, 8 gathers in flight ----
__global__ __launch_bounds__(256) void k_aggregate(const unsigned* __restrict__ nfh,
                                                   const ushort* __restrict__ srt,
                                                   const int* __restrict__ beg,
                                                   const int* __restrict__ end,
                                                   unsigned* __restrict__ aggh) {
    int wv   = (blockIdx.x * 256 + threadIdx.x) >> 6;
    int lane = threadIdx.x & 63;
    if (wv >= NN) return;
    int i = beg[wv], e = end[wv];
    float ax=0.f, ay=0.f, bx=0.f, by=0.f, cx=0.f, cy=0.f, dx=0.f, dy=0.f;
    for (; i + 7 < e; i += 8) {
        int e0 = srt[i+0]; int e1 = srt[i+1];
        int e2 = srt[i+2]; int e3 = srt[i+3];
        int e4 = srt[i+4]; int e5 = srt[i+5];
        int e6 = srt[i+6]; int e7 = srt[i+7];
        unsigned v0 = nfh[(size_t)e0 * 64 + lane];
        unsigned v1 = nfh[(size_t)e1 * 64 + lane];
        unsigned v2 = nfh[(size_t)e2 * 64 + lane];
        unsigned v3 = nfh[(size_t)e3 * 64 + lane];
        unsigned v4 = nfh[(size_t)e4 * 64 + lane];
        unsigned v5 = nfh[(size_t)e5 * 64 + lane];
        unsigned v6 = nfh[(size_t)e6 * 64 + lane];
        unsigned v7 = nfh[(size_t)e7 * 64 + lane];
        ax += bflo(v0); ay += bfhi(v0);
        bx += bflo(v1); by += bfhi(v1);
        cx += bflo(v2); cy += bfhi(v2);
        dx += bflo(v3); dy += bfhi(v3);
        ax += bflo(v4); ay += bfhi(v4);
        bx += bflo(v5); by += bfhi(v5);
        cx += bflo(v6); cy += bfhi(v6);
        dx += bflo(v7); dy += bfhi(v7);
    }
    for (; i < e; ++i) {
        unsigned v0 = nfh[(size_t)srt[i] * 64 + lane];
        ax += bflo(v0); ay += bfhi(v0);
    }
    float rx = (ax + bx) + (cx + dx);
    float ry = (ay + by) + (cy + dy);
    aggh[(size_t)wv * 64 + lane] = (unsigned)f2bf(rx) | ((unsigned)f2bf(ry) << 16);
}

// ---- 4. linear: out = aggh @ Wh.T + b  (bf16 MFMA, no LDS; R4-verified) ---
__global__ __launch_bounds__(256) void k_linear(const ushort* __restrict__ aggh,
                                                const ushort* __restrict__ Wh,
                                                const float* __restrict__ b,
                                                float* __restrict__ out) {
    int wave = threadIdx.x >> 6;
    int lane = threadIdx.x & 63;
    int R = blockIdx.x * 64 + wave * 16;
    if (R >= NN) return;
    int m = lane & 15;
    int q = lane >> 4;

    bf16x8 a[4];
    const ushort* arow = aggh + (size_t)(R + m) * D + q * 8;
    #pragma unroll
    for (int kk = 0; kk < 4; ++kk)
        a[kk] = *(const bf16x8*)(arow + kk * 32);

    #pragma unroll
    for (int c0 = 0; c0 < D; c0 += 16) {
        float bias = b[c0 + m];
        f32x4 acc = { bias, bias, bias, bias };
        const ushort* wrow = Wh + (size_t)(c0 + m) * D + q * 8;
        #pragma unroll
        for (int kk = 0; kk < 4; ++kk) {
            bf16x8 bb = *(const bf16x8*)(wrow + kk * 32);
            acc = __builtin_amdgcn_mfma_f32_16x16x32_bf16(a[kk], bb, acc, 0, 0, 0);
        }
        int row = R + q * 4;
        float* op = out + (size_t)row * D + c0 + m;
        op[0]     = acc[0];
        op[D]     = acc[1];
        op[2 * D] = acc[2];
        op[3 * D] = acc[3];
    }
}

extern "C" void kernel_launch(void* const* d_in, const int* in_sizes, int n_in,
                              void* d_out, int out_size, void* d_ws, size_t ws_size,
                              hipStream_t stream) {
    const float* nf = (const float*)d_in[0];
    const int*   ei = (const int*)d_in[1];
    const float* W  = (const float*)d_in[2];
    const float* b  = (const float*)d_in[3];
    float* out = (float*)d_out;

    // workspace (~26.4 MB; R4 proved >=29.4 MB available)
    ushort* nfh  = (ushort*)d_ws;                 // NN*D bf16 = 12.8 MB
    ushort* Wh   = nfh + (size_t)NN * D;          // 32 KB
    ushort* aggh = Wh + D * D;                    // 12.8 MB
    int* cursor  = (int*)(aggh + (size_t)NN * D); // NB
    int* beg     = cursor + NB;                   // NN
    int* end     = beg + NN;                      // NN

    // edge buffers live in d_out (25.6 MB, dead until k_linear):
    // buf: NB*CAP uint = 6.4 MB; srt: NB*CAP ushort = 3.2 MB
    unsigned* buf = (unsigned*)d_out;
    ushort*   srt = (ushort*)(buf + NB * CAP);

    k_prep     <<<(PREP_TOT + 255) / 256, 256, 0, stream>>>(nf, W, nfh, Wh, cursor);
    k_bucket   <<<NBLK_A, 256, 0, stream>>>(ei, cursor, buf);
    k_sortlocal<<<NB, 256, 0, stream>>>(cursor, buf, srt, beg, end);
    k_aggregate<<<(NN * 64 + 255) / 256, 256, 0, stream>>>((const unsigned*)nfh, srt, beg, end, (unsigned*)aggh);
    k_linear   <<<(NN + 63) / 64, 256, 0, stream>>>(aggh, Wh, b, out);
}

// Round 7
// 156.381 us; speedup vs baseline: 5.2657x; 1.0474x over previous
//
#include <hip/hip_runtime.h>

// GNN layer: out = segment_sum(nf[src], dst) @ W.T + b
// N=50000, E=800000, D=128.
// R7: fuse R6's 5 dispatches to 4. (a) k_prep_bucket: nf/W bf16-convert and
// edge bucketing are independent -> one kernel, block-range split (cursor is
// now a pure count, memset-zeroed, segment base b*CAP added at use site).
// (b) k_agg_linear: wave gathers 4 nodes -> 16x128 bf16 tile in LDS ->
// MFMA vs W from global. Removes aggh 12.8MB write+read and one dispatch.
// All scratch in d_ws (fused kernel writes d_out while others read srt).

constexpr int NN = 50000;
constexpr int NE = 800000;
constexpr int D  = 128;

constexpr int BS  = 256;                       // nodes per bucket
constexpr int NB  = (NN + BS - 1) / BS;        // 196 buckets
constexpr int CAP = 8192;                      // edges cap/bucket (mean 4096, sd 64)
constexpr int EPB = 4096;                      // edges per bucket-block
constexpr int NBLK_B = (NE + EPB - 1) / EPB;   // 196 bucket blocks

typedef __attribute__((ext_vector_type(8))) short bf16x8;
typedef __attribute__((ext_vector_type(4))) float f32x4;

__device__ inline unsigned short f2bf(float f) {           // RNE
    unsigned u = __float_as_uint(f);
    return (unsigned short)((u + 0x7fffu + ((u >> 16) & 1u)) >> 16);
}
__device__ inline float bflo(unsigned v) { return __uint_as_float(v << 16); }
__device__ inline float bfhi(unsigned v) { return __uint_as_float(v & 0xffff0000u); }

// ---- 1. fused prep (nf->bf16, W->bf16) + bucket partition -----------------
constexpr int NF4 = NN * D / 4;                           // 1,600,000
constexpr int W4  = D * D / 4;                            // 4,096
constexpr int NBLK_P = (NF4 + W4 + 255) / 256;            // 6267
constexpr int GRID_A = NBLK_B + NBLK_P;

__global__ __launch_bounds__(256) void k_prep_bucket(
    const float* __restrict__ nf, const float* __restrict__ W,
    const int* __restrict__ ei,
    ushort* __restrict__ nfh, ushort* __restrict__ Wh,
    int* __restrict__ cursor, unsigned* __restrict__ buf)
{
    __shared__ int h[NB];
    __shared__ int gbase[NB];
    __shared__ int lcur[NB];
    const int t = threadIdx.x;

    if (blockIdx.x < NBLK_B) {
        // ---- bucket branch: pk=(dst<<16)|src into exclusive dense segments
        for (int i = t; i < NB; i += 256) { h[i] = 0; lcur[i] = 0; }
        __syncthreads();
        const int e0 = blockIdx.x * EPB;
        unsigned pk[16];
        #pragma unroll
        for (int j = 0; j < 16; ++j) {
            int e = e0 + j * 256 + t;
            if (e < NE) {
                unsigned s = (unsigned)ei[e];
                unsigned d = (unsigned)ei[NE + e];
                pk[j] = (d << 16) | s;                 // bucket = pk >> 24
                atomicAdd(&h[pk[j] >> 24], 1);
            }
        }
        __syncthreads();
        for (int i = t; i < NB; i += 256)
            if (h[i] > 0) gbase[i] = i * CAP + atomicAdd(&cursor[i], h[i]);
        __syncthreads();
        #pragma unroll
        for (int j = 0; j < 16; ++j) {
            int e = e0 + j * 256 + t;
            if (e < NE) {
                unsigned b = pk[j] >> 24;
                int l = atomicAdd(&lcur[b], 1);
                buf[gbase[b] + l] = pk[j];
            }
        }
    } else {
        // ---- prep branch: bf16 conversion
        int i = (blockIdx.x - NBLK_B) * 256 + t;
        if (i < NF4) {
            float4 v = ((const float4*)nf)[i];
            ((ushort4*)nfh)[i] = make_ushort4(f2bf(v.x), f2bf(v.y), f2bf(v.z), f2bf(v.w));
        } else if (i < NF4 + W4) {
            int k = i - NF4;
            float4 v = ((const float4*)W)[k];
            ((ushort4*)Wh)[k] = make_ushort4(f2bf(v.x), f2bf(v.y), f2bf(v.z), f2bf(v.w));
        }
    }
}

// ---- 2. node-sort within each bucket segment (LDS hist+scan), emit CSR ----
__global__ __launch_bounds__(256) void k_sortlocal(const int* __restrict__ cursor,
                                                   const unsigned* __restrict__ buf,
                                                   ushort* __restrict__ srt,
                                                   int* __restrict__ beg,
                                                   int* __restrict__ end) {
    __shared__ int s[BS];
    __shared__ int cur[BS];
    const int b = blockIdx.x;
    const int t = threadIdx.x;
    const int seg = b * CAP;
    const int cnt = cursor[b];

    s[t] = 0; __syncthreads();
    for (int e = t; e < cnt; e += 256)
        atomicAdd(&s[(buf[seg + e] >> 16) & 255u], 1);
    __syncthreads();
    int myc = s[t];
    for (int off = 1; off < 256; off <<= 1) {   // inclusive scan
        int v = (t >= off) ? s[t - off] : 0;
        __syncthreads();
        s[t] += v;
        __syncthreads();
    }
    int excl = s[t] - myc;
    cur[t] = excl;
    int node = b * BS + t;
    if (node < NN) { beg[node] = seg + excl; end[node] = seg + excl + myc; }
    __syncthreads();

    for (int e = t; e < cnt; e += 256) {
        unsigned pk = buf[seg + e];
        int n = (pk >> 16) & 255u;
        int p = atomicAdd(&cur[n], 1);
        srt[seg + p] = (ushort)(pk & 0xffffu);
    }
}

// ---- 3. fused aggregate + linear ------------------------------------------
// Block = 4 waves = 16 nodes. Wave w gathers nodes base+4w..+3 (unroll-8
// bf16 gathers, fp32 accum), parks bf16 rows in LDS (row stride 136 ushort =
// 272B: write phase 2-way conflict-free, A-frag b128 read 8-way but only
// 4 reads/wave). Then wave w computes out cols [32w, 32w+32) for all 16 rows
// via 2x(4 MFMA) vs W rows from global (L2-resident, 100MB total).
constexpr int ROWU = 136;     // LDS tile row stride in ushorts (272 B, 16B-aligned)

__global__ __launch_bounds__(256) void k_agg_linear(
    const unsigned* __restrict__ nfh, const ushort* __restrict__ srt,
    const int* __restrict__ beg, const int* __restrict__ end,
    const ushort* __restrict__ Wh, const float* __restrict__ bias,
    float* __restrict__ out)
{
    __shared__ unsigned tile[16 * ROWU / 2];       // 4352 B
    const int t = threadIdx.x, lane = t & 63, w = t >> 6;
    const int base = blockIdx.x * 16;

    #pragma unroll
    for (int i = 0; i < 4; ++i) {
        const int node = base + w * 4 + i;
        int p = beg[node];
        const int e = end[node];
        float ax=0.f, ay=0.f, bx=0.f, by=0.f, cx=0.f, cy=0.f, dx=0.f, dy=0.f;
        for (; p + 7 < e; p += 8) {
            int e0 = srt[p+0]; int e1 = srt[p+1];
            int e2 = srt[p+2]; int e3 = srt[p+3];
            int e4 = srt[p+4]; int e5 = srt[p+5];
            int e6 = srt[p+6]; int e7 = srt[p+7];
            unsigned v0 = nfh[(size_t)e0 * 64 + lane];
            unsigned v1 = nfh[(size_t)e1 * 64 + lane];
            unsigned v2 = nfh[(size_t)e2 * 64 + lane];
            unsigned v3 = nfh[(size_t)e3 * 64 + lane];
            unsigned v4 = nfh[(size_t)e4 * 64 + lane];
            unsigned v5 = nfh[(size_t)e5 * 64 + lane];
            unsigned v6 = nfh[(size_t)e6 * 64 + lane];
            unsigned v7 = nfh[(size_t)e7 * 64 + lane];
            ax += bflo(v0); ay += bfhi(v0);
            bx += bflo(v1); by += bfhi(v1);
            cx += bflo(v2); cy += bfhi(v2);
            dx += bflo(v3); dy += bfhi(v3);
            ax += bflo(v4); ay += bfhi(v4);
            bx += bflo(v5); by += bfhi(v5);
            cx += bflo(v6); cy += bfhi(v6);
            dx += bflo(v7); dy += bfhi(v7);
        }
        for (; p < e; ++p) {
            unsigned v0 = nfh[(size_t)srt[p] * 64 + lane];
            ax += bflo(v0); ay += bfhi(v0);
        }
        float rx = (ax + bx) + (cx + dx);
        float ry = (ay + by) + (cy + dy);
        tile[(w * 4 + i) * (ROWU / 2) + lane] =
            (unsigned)f2bf(rx) | ((unsigned)f2bf(ry) << 16);
    }
    __syncthreads();

    const int m = lane & 15, q = lane >> 4;
    const ushort* lds = (const ushort*)tile;
    bf16x8 a[4];
    #pragma unroll
    for (int kk = 0; kk < 4; ++kk)
        a[kk] = *(const bf16x8*)(lds + m * ROWU + q * 8 + kk * 32);

    #pragma unroll
    for (int cc = 0; cc < 2; ++cc) {
        const int c0 = w * 32 + cc * 16;
        float bv = bias[c0 + m];
        f32x4 acc = { bv, bv, bv, bv };
        const ushort* wrow = Wh + (size_t)(c0 + m) * D + q * 8;
        #pragma unroll
        for (int kk = 0; kk < 4; ++kk) {
            bf16x8 bb = *(const bf16x8*)(wrow + kk * 32);
            acc = __builtin_amdgcn_mfma_f32_16x16x32_bf16(a[kk], bb, acc, 0, 0, 0);
        }
        float* op = out + (size_t)(base + q * 4) * D + c0 + m;
        op[0]     = acc[0];
        op[D]     = acc[1];
        op[2 * D] = acc[2];
        op[3 * D] = acc[3];
    }
}

extern "C" void kernel_launch(void* const* d_in, const int* in_sizes, int n_in,
                              void* d_out, int out_size, void* d_ws, size_t ws_size,
                              hipStream_t stream) {
    const float* nf = (const float*)d_in[0];
    const int*   ei = (const int*)d_in[1];
    const float* W  = (const float*)d_in[2];
    const float* b  = (const float*)d_in[3];
    float* out = (float*)d_out;

    // workspace (~22.9 MB; 29.4 MB proven available in R4)
    ushort*   nfh  = (ushort*)d_ws;                    // NN*D bf16 = 12.8 MB
    ushort*   Wh   = nfh + (size_t)NN * D;             // 32 KB
    unsigned* buf  = (unsigned*)(Wh + D * D);          // NB*CAP u32 = 6.4 MB
    ushort*   srt  = (ushort*)(buf + NB * CAP);        // NB*CAP u16 = 3.2 MB
    int*      cursor = (int*)(srt + NB * CAP);         // NB
    int*      beg  = cursor + NB;                      // NN
    int*      end  = beg + NN;                         // NN

    hipMemsetAsync(cursor, 0, NB * sizeof(int), stream);
    k_prep_bucket<<<GRID_A, 256, 0, stream>>>(nf, W, ei, nfh, Wh, cursor, buf);
    k_sortlocal  <<<NB, 256, 0, stream>>>(cursor, buf, srt, beg, end);
    k_agg_linear <<<NN / 16, 256, 0, stream>>>((const unsigned*)nfh, srt, beg, end, Wh, b, out);
}

// Round 8
// 145.648 us; speedup vs baseline: 5.6537x; 1.0737x over previous
//
#include <hip/hip_runtime.h>

// GNN layer: out = segment_sum(nf[src], dst) @ W.T + b
// N=50000, E=800000, D=128.
// R8: restore gather concurrency lost in R7's fusion. k_agg_linear: 1024-thr
// block = 16 waves, ONE node per wave (50k waves, 8 loads in flight each,
// as in R6), masked clamped batches kill the serial tail; waves 0-7 then do
// the 8 MFMA col-chunks. Buckets 256->128 nodes (NB=391), sortlocal at 512
// threads for 2x blocks / shorter serial loops.

constexpr int NN = 50000;
constexpr int NE = 800000;
constexpr int D  = 128;

constexpr int BS  = 128;                       // nodes per bucket
constexpr int NB  = (NN + BS - 1) / BS;        // 391 buckets
constexpr int CAP = 4096;                      // cap/bucket (mean 2048, sd 45)
constexpr int EPB = 4096;                      // edges per bucket-block
constexpr int NBLK_B = (NE + EPB - 1) / EPB;   // 196 bucket blocks

typedef __attribute__((ext_vector_type(8))) short bf16x8;
typedef __attribute__((ext_vector_type(4))) float f32x4;

__device__ inline unsigned short f2bf(float f) {           // RNE
    unsigned u = __float_as_uint(f);
    return (unsigned short)((u + 0x7fffu + ((u >> 16) & 1u)) >> 16);
}
__device__ inline float bflo(unsigned v) { return __uint_as_float(v << 16); }
__device__ inline float bfhi(unsigned v) { return __uint_as_float(v & 0xffff0000u); }

// ---- 1. fused prep (nf->bf16, W->bf16) + bucket partition -----------------
constexpr int NF4 = NN * D / 4;                           // 1,600,000
constexpr int W4  = D * D / 4;                            // 4,096
constexpr int NBLK_P = (NF4 + W4 + 255) / 256;            // 6267
constexpr int GRID_A = NBLK_B + NBLK_P;

__global__ __launch_bounds__(256) void k_prep_bucket(
    const float* __restrict__ nf, const float* __restrict__ W,
    const int* __restrict__ ei,
    ushort* __restrict__ nfh, ushort* __restrict__ Wh,
    int* __restrict__ cursor, unsigned* __restrict__ buf)
{
    __shared__ int h[NB];
    __shared__ int gbase[NB];
    __shared__ int lcur[NB];
    const int t = threadIdx.x;

    if (blockIdx.x < NBLK_B) {
        // bucket branch: pk=(dst<<16)|src into exclusive dense segments
        for (int i = t; i < NB; i += 256) { h[i] = 0; lcur[i] = 0; }
        __syncthreads();
        const int e0 = blockIdx.x * EPB;
        unsigned pk[16];
        #pragma unroll
        for (int j = 0; j < 16; ++j) {
            int e = e0 + j * 256 + t;
            if (e < NE) {
                unsigned s = (unsigned)ei[e];
                unsigned d = (unsigned)ei[NE + e];
                pk[j] = (d << 16) | s;                 // bucket = pk >> 23
                atomicAdd(&h[pk[j] >> 23], 1);
            }
        }
        __syncthreads();
        for (int i = t; i < NB; i += 256)
            if (h[i] > 0) gbase[i] = i * CAP + atomicAdd(&cursor[i], h[i]);
        __syncthreads();
        #pragma unroll
        for (int j = 0; j < 16; ++j) {
            int e = e0 + j * 256 + t;
            if (e < NE) {
                unsigned b = pk[j] >> 23;
                int l = atomicAdd(&lcur[b], 1);
                buf[gbase[b] + l] = pk[j];
            }
        }
    } else {
        // prep branch: bf16 conversion
        int i = (blockIdx.x - NBLK_B) * 256 + t;
        if (i < NF4) {
            float4 v = ((const float4*)nf)[i];
            ((ushort4*)nfh)[i] = make_ushort4(f2bf(v.x), f2bf(v.y), f2bf(v.z), f2bf(v.w));
        } else if (i < NF4 + W4) {
            int k = i - NF4;
            float4 v = ((const float4*)W)[k];
            ((ushort4*)Wh)[k] = make_ushort4(f2bf(v.x), f2bf(v.y), f2bf(v.z), f2bf(v.w));
        }
    }
}

// ---- 2. node-sort within each bucket segment (LDS hist+scan), emit CSR ----
__global__ __launch_bounds__(512) void k_sortlocal(const int* __restrict__ cursor,
                                                   const unsigned* __restrict__ buf,
                                                   ushort* __restrict__ srt,
                                                   int* __restrict__ beg,
                                                   int* __restrict__ end) {
    __shared__ int s[BS];
    __shared__ int cur[BS];
    const int b = blockIdx.x;
    const int t = threadIdx.x;
    const int seg = b * CAP;
    const int cnt = cursor[b];

    if (t < BS) s[t] = 0;
    __syncthreads();
    for (int e = t; e < cnt; e += 512)
        atomicAdd(&s[(buf[seg + e] >> 16) & (BS - 1)], 1);
    __syncthreads();
    int myc = (t < BS) ? s[t] : 0;
    for (int off = 1; off < BS; off <<= 1) {    // inclusive scan over BS=128
        int v = (t >= off && t < BS) ? s[t - off] : 0;
        __syncthreads();
        if (t < BS) s[t] += v;
        __syncthreads();
    }
    if (t < BS) {
        int excl = s[t] - myc;
        cur[t] = excl;
        int node = b * BS + t;
        if (node < NN) { beg[node] = seg + excl; end[node] = seg + excl + myc; }
    }
    __syncthreads();

    for (int e = t; e < cnt; e += 512) {
        unsigned pk = buf[seg + e];
        int n = (pk >> 16) & (BS - 1);
        int p = atomicAdd(&cur[n], 1);
        srt[seg + p] = (ushort)(pk & 0xffffu);
    }
}

// ---- 3. fused aggregate + linear ------------------------------------------
// Block = 1024 threads = 16 waves = 16 nodes, one node per wave (max MLP).
// Masked clamped batch of 8: always 8 gathers in flight, no scalar tail.
// Waves 0-7 then each compute one 16-col chunk via 4 MFMA vs W from global.
constexpr int ROWU = 136;     // LDS tile row stride in ushorts (272 B)

__global__ __launch_bounds__(1024) void k_agg_linear(
    const unsigned* __restrict__ nfh, const ushort* __restrict__ srt,
    const int* __restrict__ beg, const int* __restrict__ end,
    const ushort* __restrict__ Wh, const float* __restrict__ bias,
    float* __restrict__ out)
{
    __shared__ unsigned tile[16 * ROWU / 2];       // 4352 B
    const int t = threadIdx.x, lane = t & 63, w = t >> 6;
    const int base = blockIdx.x * 16;
    const int node = base + w;                     // grid exact: 3125*16=50000

    int p = beg[node];
    const int e = end[node];
    float ax=0.f, ay=0.f, bx=0.f, by=0.f, cx=0.f, cy=0.f, dx=0.f, dy=0.f;
    for (; p < e; p += 8) {
        const int lim = e - 1;
        unsigned v[8]; float msk[8];
        #pragma unroll
        for (int j = 0; j < 8; ++j) {
            int pos = p + j;
            msk[j] = (pos <= lim) ? 1.f : 0.f;
            if (pos > lim) pos = lim;              // clamp: safe, L1-warm dup
            v[j] = nfh[(size_t)srt[pos] * 64 + lane];
        }
        ax += msk[0] * bflo(v[0]); ay += msk[0] * bfhi(v[0]);
        bx += msk[1] * bflo(v[1]); by += msk[1] * bfhi(v[1]);
        cx += msk[2] * bflo(v[2]); cy += msk[2] * bfhi(v[2]);
        dx += msk[3] * bflo(v[3]); dy += msk[3] * bfhi(v[3]);
        ax += msk[4] * bflo(v[4]); ay += msk[4] * bfhi(v[4]);
        bx += msk[5] * bflo(v[5]); by += msk[5] * bfhi(v[5]);
        cx += msk[6] * bflo(v[6]); cy += msk[6] * bfhi(v[6]);
        dx += msk[7] * bflo(v[7]); dy += msk[7] * bfhi(v[7]);
    }
    float rx = (ax + bx) + (cx + dx);
    float ry = (ay + by) + (cy + dy);
    tile[w * (ROWU / 2) + lane] = (unsigned)f2bf(rx) | ((unsigned)f2bf(ry) << 16);
    __syncthreads();

    if (w < 8) {
        const int m = lane & 15, q = lane >> 4;
        const ushort* lds = (const ushort*)tile;
        bf16x8 a[4];
        #pragma unroll
        for (int kk = 0; kk < 4; ++kk)
            a[kk] = *(const bf16x8*)(lds + m * ROWU + q * 8 + kk * 32);

        const int c0 = w * 16;
        float bv = bias[c0 + m];
        f32x4 acc = { bv, bv, bv, bv };
        const ushort* wrow = Wh + (size_t)(c0 + m) * D + q * 8;
        #pragma unroll
        for (int kk = 0; kk < 4; ++kk) {
            bf16x8 bb = *(const bf16x8*)(wrow + kk * 32);
            acc = __builtin_amdgcn_mfma_f32_16x16x32_bf16(a[kk], bb, acc, 0, 0, 0);
        }
        float* op = out + (size_t)(base + q * 4) * D + c0 + m;
        op[0]     = acc[0];
        op[D]     = acc[1];
        op[2 * D] = acc[2];
        op[3 * D] = acc[3];
    }
}

extern "C" void kernel_launch(void* const* d_in, const int* in_sizes, int n_in,
                              void* d_out, int out_size, void* d_ws, size_t ws_size,
                              hipStream_t stream) {
    const float* nf = (const float*)d_in[0];
    const int*   ei = (const int*)d_in[1];
    const float* W  = (const float*)d_in[2];
    const float* b  = (const float*)d_in[3];
    float* out = (float*)d_out;

    // workspace (~22.9 MB; 29.4 MB proven available in R4)
    ushort*   nfh  = (ushort*)d_ws;                    // NN*D bf16 = 12.8 MB
    ushort*   Wh   = nfh + (size_t)NN * D;             // 32 KB
    unsigned* buf  = (unsigned*)(Wh + D * D);          // NB*CAP u32 = 6.4 MB
    ushort*   srt  = (ushort*)(buf + NB * CAP);        // NB*CAP u16 = 3.2 MB
    int*      cursor = (int*)(srt + NB * CAP);         // NB
    int*      beg  = cursor + NB;                      // NN
    int*      end  = beg + NN;                         // NN

    hipMemsetAsync(cursor, 0, NB * sizeof(int), stream);
    k_prep_bucket<<<GRID_A, 256, 0, stream>>>(nf, W, ei, nfh, Wh, cursor, buf);
    k_sortlocal  <<<NB, 512, 0, stream>>>(cursor, buf, srt, beg, end);
    k_agg_linear <<<NN / 16, 1024, 0, stream>>>((const unsigned*)nfh, srt, beg, end, Wh, b, out);
}